// Round 4
// baseline (322.536 us; speedup 1.0000x reference)
//
#include <hip/hip_runtime.h>
#include <hip/hip_bf16.h>

// TensorTrainLMN: out[b, a*128+h] = X[b,:] @ W[:, a*128+h] + bias
//   X[b] = [nh[b,0,:128], ..., nh[b,15,:128], te[b,:128]]   (K = 2176)
// tt_fold: folds A@B^(15-c)@U_out (exact f32) into W, bf16, PRE-PACKED as the
//   GEMM's byte-linear LDS B-tile image: [n_blk][kt][slot=kk*4+lg][n 0..255][8].
// tt_gemm: 256x256x64 bf16 MFMA GEMM, m201-style 4-phase schedule:
//   per phase {ds_read subtile | stage-issue; s_barrier; setprio(1); 16 MFMA;
//   setprio(0); s_barrier}; B via global_load_lds width 16 (issued phase 0,
//   waited 3 phases later at the single vmcnt(0)+lgkm(0) publish barrier);
//   A reg-staged f32->bf16 in two halves (issue p0/p1, cvt+ds_write p2/p3).

typedef short bf16x8 __attribute__((ext_vector_type(8)));
typedef float f32x4  __attribute__((ext_vector_type(4)));

__device__ __forceinline__ unsigned f2bfbits(float f) {
    unsigned u = __builtin_bit_cast(unsigned, f);
    return (u + 0x7FFFu + ((u >> 16) & 1u)) >> 16;   // round-to-nearest-even
}
__device__ __forceinline__ unsigned pack2(float a, float b) {
    return f2bfbits(a) | (f2bfbits(b) << 16);
}

// ---------------------------------------------------------------------------
// Fold kernel: 72 blocks x 256 threads (verified in rounds 2-3).
// ---------------------------------------------------------------------------
__global__ __launch_bounds__(256) void tt_fold(
    const float* __restrict__ Ag,    // (4,128,64)
    const float* __restrict__ Bg,    // (4,64,64)
    const float* __restrict__ Abg,   // (4,1,64)
    const float* __restrict__ Utg,   // (4,128,64)
    const float* __restrict__ btg,   // (4,1,64)
    const float* __restrict__ Uog,   // (4,64,128)
    const float* __restrict__ bog,   // (4,1,128)
    unsigned short* __restrict__ Wp, // pre-packed W tile image (2*34*16384 shorts)
    float* __restrict__ biasOut)     // [512]
{
    __shared__ __align__(16) float L[16384];
    const int t = threadIdx.x;
    const int bid = blockIdx.x;

    auto mm = [&](float* d, const float* x, const float* y, const float* add) {
        const int r = t >> 2, c0 = (t & 3) << 4;
        float acc[16];
#pragma unroll
        for (int j = 0; j < 16; ++j) acc[j] = 0.f;
        for (int k = 0; k < 64; ++k) {
            const float a = x[r * 64 + k];
            const float4* yr = (const float4*)(y + k * 64 + c0);
#pragma unroll
            for (int jj = 0; jj < 4; ++jj) {
                float4 v = yr[jj];
                acc[4 * jj + 0] += a * v.x;
                acc[4 * jj + 1] += a * v.y;
                acc[4 * jj + 2] += a * v.z;
                acc[4 * jj + 3] += a * v.w;
            }
        }
        if (add) {
#pragma unroll
            for (int j = 0; j < 16; ++j) acc[j] += add[r * 64 + c0 + j];
        }
#pragma unroll
        for (int j = 0; j < 16; ++j) d[r * 64 + c0 + j] = acc[j];
    };

    float* buf[4];
    buf[0] = L;
    buf[1] = L + 4096;
    buf[2] = L + 8192;
    buf[3] = L + 12288;

    if (bid < 68) {
        int a, p, kbase;
        const float* src;
        if (bid < 64) { a = bid >> 4; const int c = bid & 15; p = 15 - c; kbase = c * 128; src = Ag  + a * 8192; }
        else          { a = bid - 64; p = 16; kbase = 2048;               src = Utg + a * 8192; }
        const float* Bmat = Bg + a * 4096;

        for (int i = t; i < 4096; i += 256) {
            buf[0][i] = Bmat[i];
            buf[2][i] = ((i >> 6) == (i & 63)) ? 1.f : 0.f;
        }
        __syncthreads();
        int bcur = 0, rcur = 2;
        int e = p;
        while (e) {
            if (e & 1) { mm(buf[rcur ^ 1], buf[rcur], buf[bcur], nullptr); rcur ^= 1; __syncthreads(); }
            e >>= 1;
            if (e)     { mm(buf[bcur ^ 1], buf[bcur], buf[bcur], nullptr); bcur ^= 1; __syncthreads(); }
        }

        {
            float tmp[16];
#pragma unroll
            for (int j = 0; j < 16; ++j) tmp[j] = buf[rcur][t * 16 + j];
            __syncthreads();
            float* P = L + 8320;
#pragma unroll
            for (int j = 0; j < 16; ++j) P[t * 16 + j] = tmp[j];
        }
        __syncthreads();

        // M1 = src(128x64) @ P, stride-65
        const float* P = L + 8320;
        float* M1 = L;
        {
            const int i = t >> 1, r0 = (t & 1) << 5;
            float acc[32];
#pragma unroll
            for (int j = 0; j < 32; ++j) acc[j] = 0.f;
            for (int q = 0; q < 64; ++q) {
                const float av = src[i * 64 + q];
                const float4* pr = (const float4*)(P + q * 64 + r0);
#pragma unroll
                for (int jj = 0; jj < 8; ++jj) {
                    float4 v = pr[jj];
                    acc[4 * jj + 0] += av * v.x;
                    acc[4 * jj + 1] += av * v.y;
                    acc[4 * jj + 2] += av * v.z;
                    acc[4 * jj + 3] += av * v.w;
                }
            }
#pragma unroll
            for (int j = 0; j < 32; ++j) M1[i * 65 + r0 + j] = acc[j];
        }
        __syncthreads();

        // W2 = M1(128x64) @ Uo(64x128)
        const float* UoA = Uog + a * 8192;
        float* UC = L + 12416;
        const int i = t >> 1, h0 = (t & 1) << 6;
        float acc2[64];
#pragma unroll
        for (int j = 0; j < 64; ++j) acc2[j] = 0.f;
        for (int ch = 0; ch < 4; ++ch) {
            __syncthreads();
            for (int idx = t; idx < 2048; idx += 256) UC[idx] = UoA[ch * 2048 + idx];
            __syncthreads();
            for (int rr = 0; rr < 16; ++rr) {
                const float m = M1[i * 65 + ch * 16 + rr];
                const float4* ur = (const float4*)(UC + rr * 128 + h0);
#pragma unroll
                for (int jj = 0; jj < 16; ++jj) {
                    float4 v = ur[jj];
                    acc2[4 * jj + 0] += m * v.x;
                    acc2[4 * jj + 1] += m * v.y;
                    acc2[4 * jj + 2] += m * v.z;
                    acc2[4 * jj + 3] += m * v.w;
                }
            }
        }
        // write pre-packed: slot = (k>>3)&7 == kk*4+lg, byte-linear LDS image
        {
            const int k = kbase + i;
            const int kt = k >> 6, slot = (k >> 3) & 7, widx = k & 7;
#pragma unroll
            for (int j = 0; j < 64; ++j) {
                const int n = a * 128 + h0 + j;
                const int n_blk = n >> 8, n_loc = n & 255;
                Wp[(size_t)((n_blk * 34 + kt) * 8 + slot) * 2048 + n_loc * 8 + widx] =
                    (unsigned short)f2bfbits(acc2[j]);
            }
        }
    } else {
        // bias: S16 = sum_{p<16} B^p, B16 = B^16
        const int a = bid - 68;
        const float* Bmat = Bg + a * 4096;
        for (int i = t; i < 4096; i += 256) {
            buf[0][i] = Bmat[i];
            buf[2][i] = ((i >> 6) == (i & 63)) ? 1.f : 0.f;
        }
        __syncthreads();
        int bcur = 0, scur = 2;
        for (int rnd = 0; rnd < 4; ++rnd) {
            mm(buf[scur ^ 1], buf[bcur], buf[scur], buf[scur]);
            mm(buf[bcur ^ 1], buf[bcur], buf[bcur], nullptr);
            __syncthreads();
            scur ^= 1; bcur ^= 1;
        }
        float* vv = buf[3];
        if (t < 64) {
            float acc = 0.f;
            const float* S16 = buf[scur];
            const float* B16 = buf[bcur];
            for (int q = 0; q < 64; ++q)
                acc += Abg[a * 64 + q] * S16[q * 64 + t]
                     + btg[a * 64 + q] * B16[q * 64 + t];
            vv[t] = acc;
        }
        __syncthreads();
        if (t < 128) {
            float accb = bog[a * 128 + t];
            const float* UoA = Uog + a * 8192;
            for (int r = 0; r < 64; ++r) accb += vv[r] * UoA[r * 128 + t];
            biasOut[a * 128 + t] = accb;
        }
    }
}

// ---------------------------------------------------------------------------
// Main GEMM, 4-phase m201-style schedule. 256 blocks x 512 threads.
// LDS: A [d][kk][lg][row][16B] @0 (2x32K), B same @64K.
// ---------------------------------------------------------------------------
__global__ __launch_bounds__(512, 2) void tt_gemm(
    const float* __restrict__ nh,           // (32768,16,128)
    const float* __restrict__ te,           // (32768,128)
    const unsigned short* __restrict__ Wp,  // pre-packed tiles
    const float* __restrict__ bias,         // [512]
    float* __restrict__ out)                // (32768,512)
{
    __shared__ __align__(16) char Lds[131072];

    const int t = threadIdx.x;
    const int lane = t & 63, wave = t >> 6;
    const int lt = ((blockIdx.x & 7) * 32) + (blockIdx.x >> 3);  // XCD chunks
    const int m0 = (lt >> 1) * 256;
    const int nblk = lt & 1, n0 = nblk * 256;

    const int wr = wave >> 2, wc = wave & 3;     // 2(M) x 4(N) wave grid
    const int lx = lane & 15, lg = lane >> 4;

    // A staging: thread -> row r (0..255), k-half kh (32 floats)
    const int r = t >> 1, kh = t & 1;
    const float* nhp = nh + (size_t)(m0 + r) * 2048 + kh * 32;
    const float* tep = te + (size_t)(m0 + r) * 128  + kh * 32;

    // B staging source: per-lane global byte address (linear memcpy image)
    const char* const wsrc = (const char*)Wp + (size_t)nblk * 34 * 32768
                             + wave * 1024 + lane * 16;   // + kt*32768 + j*8192

    char* const Ab = Lds;              // + d*32768 + kk*16384 + lg*4096 + row*16
    char* const Bb = Lds + 65536;

    // frag read bases (within a buffer)
    const int aoff = lg * 4096 + (wr * 128 + lx) * 16;   // + kk*16384 + fm*256
    const int boff = lg * 4096 + (wc * 64  + lx) * 16;   // + kk*16384 + fn*256
    // A ds_write base: + lg*4096 (lg of the half), within buffer
    const int awoff = kh * 16384 + r * 16;

    f32x4 acc[8][4] = {};

#define GLOADB(dst, kt_) do {                                                  \
    const char* _gs = wsrc + (size_t)(kt_) * 32768;                            \
    char* _ld = Bb + (dst) * 32768 + wave * 1024;                              \
    _Pragma("unroll")                                                          \
    for (int _j = 0; _j < 4; ++_j)                                             \
        __builtin_amdgcn_global_load_lds(                                      \
            (const __attribute__((address_space(1))) unsigned int*)(_gs + _j * 8192), \
            (__attribute__((address_space(3))) unsigned int*)(_ld + _j * 8192),\
            16, 0, 0);                                                         \
} while (0)

    // ---- prologue: stage tile 0 into buffer 0 ----
    GLOADB(0, 0);
    {
        const float* p = nhp;                 // kt=0 is in nh
        float4 v[8];
#pragma unroll
        for (int j = 0; j < 8; ++j) v[j] = *(const float4*)(p + 4 * j);
#pragma unroll
        for (int g = 0; g < 4; ++g) {
            uint4 w;
            w.x = pack2(v[2 * g].x,     v[2 * g].y);
            w.y = pack2(v[2 * g].z,     v[2 * g].w);
            w.z = pack2(v[2 * g + 1].x, v[2 * g + 1].y);
            w.w = pack2(v[2 * g + 1].z, v[2 * g + 1].w);
            *(uint4*)(Ab + awoff + g * 4096) = w;
        }
    }
    asm volatile("s_waitcnt vmcnt(0) lgkmcnt(0)" ::: "memory");
    __builtin_amdgcn_s_barrier();

    int d = 0;
#pragma unroll 1
    for (int kt = 0; kt < 34; ++kt) {
        const bool st = (kt + 1) < 34;
        const float* pnext = ((kt + 1) < 32) ? (nhp + (kt + 1) * 64)
                                             : (tep + (kt + 1 - 32) * 64);
        const char* Abase = Ab + d * 32768;
        const char* Bbase = Bb + d * 32768;

        bf16x8 aF0[2][4], aF1[2][4], b01[2][2], b23[2][2];
        float4 h0[4], h1[4];

        // ================= phase 0 : Q00 (fm0-3 x fn0-1) =================
        if (st) GLOADB(d ^ 1, kt + 1);                       // B(kt+1), waited at p3
        if (st) {
#pragma unroll
            for (int j = 0; j < 4; ++j) h0[j] = *(const float4*)(pnext + 4 * j);
        }
#pragma unroll
        for (int kk = 0; kk < 2; ++kk) {
#pragma unroll
            for (int fm = 0; fm < 4; ++fm)
                aF0[kk][fm] = *(const bf16x8*)(Abase + kk * 16384 + aoff + fm * 256);
#pragma unroll
            for (int fn = 0; fn < 2; ++fn)
                b01[kk][fn] = *(const bf16x8*)(Bbase + kk * 16384 + boff + fn * 256);
        }
        __builtin_amdgcn_s_barrier();
        __builtin_amdgcn_s_setprio(1);
#pragma unroll
        for (int fm = 0; fm < 4; ++fm)
#pragma unroll
            for (int fn = 0; fn < 2; ++fn)
#pragma unroll
                for (int kk = 0; kk < 2; ++kk)
                    acc[fm][fn] = __builtin_amdgcn_mfma_f32_16x16x32_bf16(
                        aF0[kk][fm], b01[kk][fn], acc[fm][fn], 0, 0, 0);
        __builtin_amdgcn_s_setprio(0);
        __builtin_amdgcn_s_barrier();

        // ================= phase 1 : Q01 (fm0-3 x fn2-3) =================
        if (st) {
#pragma unroll
            for (int j = 0; j < 4; ++j) h1[j] = *(const float4*)(pnext + 16 + 4 * j);
        }
#pragma unroll
        for (int kk = 0; kk < 2; ++kk)
#pragma unroll
            for (int fn = 0; fn < 2; ++fn)
                b23[kk][fn] = *(const bf16x8*)(Bbase + kk * 16384 + boff + (fn + 2) * 256);
        __builtin_amdgcn_s_barrier();
        __builtin_amdgcn_s_setprio(1);
#pragma unroll
        for (int fm = 0; fm < 4; ++fm)
#pragma unroll
            for (int fn = 0; fn < 2; ++fn)
#pragma unroll
                for (int kk = 0; kk < 2; ++kk)
                    acc[fm][fn + 2] = __builtin_amdgcn_mfma_f32_16x16x32_bf16(
                        aF0[kk][fm], b23[kk][fn], acc[fm][fn + 2], 0, 0, 0);
        __builtin_amdgcn_s_setprio(0);
        __builtin_amdgcn_s_barrier();

        // ================= phase 2 : Q10 (fm4-7 x fn0-1) =================
        if (st) {                                            // cvt + write half 0
#pragma unroll
            for (int g = 0; g < 2; ++g) {
                uint4 w;
                w.x = pack2(h0[2 * g].x,     h0[2 * g].y);
                w.y = pack2(h0[2 * g].z,     h0[2 * g].w);
                w.z = pack2(h0[2 * g + 1].x, h0[2 * g + 1].y);
                w.w = pack2(h0[2 * g + 1].z, h0[2 * g + 1].w);
                *(uint4*)(Ab + (d ^ 1) * 32768 + awoff + g * 4096) = w;
            }
        }
#pragma unroll
        for (int kk = 0; kk < 2; ++kk)
#pragma unroll
            for (int fm = 0; fm < 4; ++fm)
                aF1[kk][fm] = *(const bf16x8*)(Abase + kk * 16384 + aoff + (fm + 4) * 256);
        __builtin_amdgcn_s_barrier();
        __builtin_amdgcn_s_setprio(1);
#pragma unroll
        for (int fm = 0; fm < 4; ++fm)
#pragma unroll
            for (int fn = 0; fn < 2; ++fn)
#pragma unroll
                for (int kk = 0; kk < 2; ++kk)
                    acc[fm + 4][fn] = __builtin_amdgcn_mfma_f32_16x16x32_bf16(
                        aF1[kk][fm], b01[kk][fn], acc[fm + 4][fn], 0, 0, 0);
        __builtin_amdgcn_s_setprio(0);
        __builtin_amdgcn_s_barrier();

        // ================= phase 3 : Q11 (fm4-7 x fn2-3) =================
        if (st) {                                            // cvt + write half 1
#pragma unroll
            for (int g = 0; g < 2; ++g) {
                uint4 w;
                w.x = pack2(h1[2 * g].x,     h1[2 * g].y);
                w.y = pack2(h1[2 * g].z,     h1[2 * g].w);
                w.z = pack2(h1[2 * g + 1].x, h1[2 * g + 1].y);
                w.w = pack2(h1[2 * g + 1].z, h1[2 * g + 1].w);
                *(uint4*)(Ab + (d ^ 1) * 32768 + awoff + (g + 2) * 4096) = w;
            }
        }
        __builtin_amdgcn_s_barrier();
        __builtin_amdgcn_s_setprio(1);
#pragma unroll
        for (int fm = 0; fm < 4; ++fm)
#pragma unroll
            for (int fn = 0; fn < 2; ++fn)
#pragma unroll
                for (int kk = 0; kk < 2; ++kk)
                    acc[fm + 4][fn + 2] = __builtin_amdgcn_mfma_f32_16x16x32_bf16(
                        aF1[kk][fm], b23[kk][fn], acc[fm + 4][fn + 2], 0, 0, 0);
        __builtin_amdgcn_s_setprio(0);
        // publish barrier: B(kt+1) gloads are 3 phases old, A-loads already
        // consumed by the cvts -> this drain is (nearly) free.
        asm volatile("s_waitcnt vmcnt(0) lgkmcnt(0)" ::: "memory");
        __builtin_amdgcn_s_barrier();

        d ^= 1;
    }
#undef GLOADB

    // epilogue: C/D layout col = lane&15, row = (lane>>4)*4 + reg  [m89]
    const int orow = m0 + wr * 128 + lg * 4;
    const int ocol = n0 + wc * 64 + lx;
    float bv[4];
#pragma unroll
    for (int fn = 0; fn < 4; ++fn) bv[fn] = bias[ocol + fn * 16];
#pragma unroll
    for (int fm = 0; fm < 8; ++fm)
#pragma unroll
        for (int fn = 0; fn < 4; ++fn)
#pragma unroll
            for (int j = 0; j < 4; ++j)
                out[(size_t)(orow + fm * 16 + j) * 512 + ocol + fn * 16] =
                    acc[fm][fn][j] + bv[fn];
}

// ---------------------------------------------------------------------------
extern "C" void kernel_launch(void* const* d_in, const int* in_sizes, int n_in,
                              void* d_out, int out_size, void* d_ws, size_t ws_size,
                              hipStream_t stream) {
    const float* nh  = (const float*)d_in[0];
    const float* te  = (const float*)d_in[1];
    const float* Ag  = (const float*)d_in[2];
    const float* Bg  = (const float*)d_in[3];
    const float* Abg = (const float*)d_in[4];
    const float* Utg = (const float*)d_in[5];
    const float* btg = (const float*)d_in[6];
    const float* Uog = (const float*)d_in[7];
    const float* bog = (const float*)d_in[8];

    unsigned short* Wp = (unsigned short*)d_ws;              // 2*34*16384*2 B
    float* bias = (float*)((char*)d_ws + (size_t)2 * 34 * 16384 * 2);
    float* out = (float*)d_out;

    hipLaunchKernelGGL(tt_fold, dim3(72), dim3(256), 0, stream,
                       Ag, Bg, Abg, Utg, btg, Uog, bog, Wp, bias);
    hipLaunchKernelGGL(tt_gemm, dim3(256), dim3(512), 0, stream,
                       nh, te, Wp, bias, out);
}

// Round 5
// 238.374 us; speedup vs baseline: 1.3531x; 1.3531x over previous
//
#include <hip/hip_runtime.h>
#include <hip/hip_bf16.h>

// TensorTrainLMN: out[b, a*128+h] = X[b,:] @ W[:, a*128+h] + bias
//   X[b] = [nh[b,0,:128], ..., nh[b,15,:128], te[b,:128]]   (K = 2176)
// tt_fold: folds A@B^(15-c)@U_out (exact f32) into W bf16, PRE-PACKED in MFMA
//   B-fragment order: Wp[kt][slot=k8][n 0..511][8 bf16]  (kt=k/64, slot=(k/8)%8)
// tt_gemm: LDS-for-A-only MFMA GEMM. W is 2.2MB = L2-resident, so B-frags are
//   loaded global->VGPR directly (coalesced, frag-ordered). 256-thr blocks
//   (4 waves, 1/SIMD), block tile 64Mx256N, wave tile 64x64, one barrier per
//   K-tile, ~3 independent blocks/CU interleave to hide all latencies.

typedef short bf16x8 __attribute__((ext_vector_type(8)));
typedef float f32x4  __attribute__((ext_vector_type(4)));

__device__ __forceinline__ unsigned f2bfbits(float f) {
    unsigned u = __builtin_bit_cast(unsigned, f);
    return (u + 0x7FFFu + ((u >> 16) & 1u)) >> 16;   // round-to-nearest-even
}
__device__ __forceinline__ unsigned pack2(float a, float b) {
    return f2bfbits(a) | (f2bfbits(b) << 16);
}

// ---------------------------------------------------------------------------
// Fold kernel: 72 blocks x 256 threads (math verified rounds 2-4; only the
// Wp indexing is the single-image fragment layout now).
// ---------------------------------------------------------------------------
__global__ __launch_bounds__(256) void tt_fold(
    const float* __restrict__ Ag,    // (4,128,64)
    const float* __restrict__ Bg,    // (4,64,64)
    const float* __restrict__ Abg,   // (4,1,64)
    const float* __restrict__ Utg,   // (4,128,64)
    const float* __restrict__ btg,   // (4,1,64)
    const float* __restrict__ Uog,   // (4,64,128)
    const float* __restrict__ bog,   // (4,1,128)
    unsigned short* __restrict__ Wp, // [34][8][512][8] bf16
    float* __restrict__ biasOut)     // [512]
{
    __shared__ __align__(16) float L[16384];
    const int t = threadIdx.x;
    const int bid = blockIdx.x;

    auto mm = [&](float* d, const float* x, const float* y, const float* add) {
        const int r = t >> 2, c0 = (t & 3) << 4;
        float acc[16];
#pragma unroll
        for (int j = 0; j < 16; ++j) acc[j] = 0.f;
        for (int k = 0; k < 64; ++k) {
            const float a = x[r * 64 + k];
            const float4* yr = (const float4*)(y + k * 64 + c0);
#pragma unroll
            for (int jj = 0; jj < 4; ++jj) {
                float4 v = yr[jj];
                acc[4 * jj + 0] += a * v.x;
                acc[4 * jj + 1] += a * v.y;
                acc[4 * jj + 2] += a * v.z;
                acc[4 * jj + 3] += a * v.w;
            }
        }
        if (add) {
#pragma unroll
            for (int j = 0; j < 16; ++j) acc[j] += add[r * 64 + c0 + j];
        }
#pragma unroll
        for (int j = 0; j < 16; ++j) d[r * 64 + c0 + j] = acc[j];
    };

    float* buf[4];
    buf[0] = L;
    buf[1] = L + 4096;
    buf[2] = L + 8192;
    buf[3] = L + 12288;

    if (bid < 68) {
        int a, p, kbase;
        const float* src;
        if (bid < 64) { a = bid >> 4; const int c = bid & 15; p = 15 - c; kbase = c * 128; src = Ag  + a * 8192; }
        else          { a = bid - 64; p = 16; kbase = 2048;               src = Utg + a * 8192; }
        const float* Bmat = Bg + a * 4096;

        for (int i = t; i < 4096; i += 256) {
            buf[0][i] = Bmat[i];
            buf[2][i] = ((i >> 6) == (i & 63)) ? 1.f : 0.f;
        }
        __syncthreads();
        int bcur = 0, rcur = 2;
        int e = p;
        while (e) {
            if (e & 1) { mm(buf[rcur ^ 1], buf[rcur], buf[bcur], nullptr); rcur ^= 1; __syncthreads(); }
            e >>= 1;
            if (e)     { mm(buf[bcur ^ 1], buf[bcur], buf[bcur], nullptr); bcur ^= 1; __syncthreads(); }
        }

        {
            float tmp[16];
#pragma unroll
            for (int j = 0; j < 16; ++j) tmp[j] = buf[rcur][t * 16 + j];
            __syncthreads();
            float* P = L + 8320;
#pragma unroll
            for (int j = 0; j < 16; ++j) P[t * 16 + j] = tmp[j];
        }
        __syncthreads();

        // M1 = src(128x64) @ P, stride-65
        const float* P = L + 8320;
        float* M1 = L;
        {
            const int i = t >> 1, r0 = (t & 1) << 5;
            float acc[32];
#pragma unroll
            for (int j = 0; j < 32; ++j) acc[j] = 0.f;
            for (int q = 0; q < 64; ++q) {
                const float av = src[i * 64 + q];
                const float4* pr = (const float4*)(P + q * 64 + r0);
#pragma unroll
                for (int jj = 0; jj < 8; ++jj) {
                    float4 v = pr[jj];
                    acc[4 * jj + 0] += av * v.x;
                    acc[4 * jj + 1] += av * v.y;
                    acc[4 * jj + 2] += av * v.z;
                    acc[4 * jj + 3] += av * v.w;
                }
            }
#pragma unroll
            for (int j = 0; j < 32; ++j) M1[i * 65 + r0 + j] = acc[j];
        }
        __syncthreads();

        // W2 = M1(128x64) @ Uo(64x128)
        const float* UoA = Uog + a * 8192;
        float* UC = L + 12416;
        const int i = t >> 1, h0 = (t & 1) << 6;
        float acc2[64];
#pragma unroll
        for (int j = 0; j < 64; ++j) acc2[j] = 0.f;
        for (int ch = 0; ch < 4; ++ch) {
            __syncthreads();
            for (int idx = t; idx < 2048; idx += 256) UC[idx] = UoA[ch * 2048 + idx];
            __syncthreads();
            for (int rr = 0; rr < 16; ++rr) {
                const float m = M1[i * 65 + ch * 16 + rr];
                const float4* ur = (const float4*)(UC + rr * 128 + h0);
#pragma unroll
                for (int jj = 0; jj < 16; ++jj) {
                    float4 v = ur[jj];
                    acc2[4 * jj + 0] += m * v.x;
                    acc2[4 * jj + 1] += m * v.y;
                    acc2[4 * jj + 2] += m * v.z;
                    acc2[4 * jj + 3] += m * v.w;
                }
            }
        }
        // write single-image fragment layout: [kt][slot][n][widx]
        {
            const int k = kbase + i;
            const int kt = k >> 6, slot = (k >> 3) & 7, widx = k & 7;
#pragma unroll
            for (int j = 0; j < 64; ++j) {
                const int n = a * 128 + h0 + j;
                Wp[((size_t)(kt * 8 + slot) * 512 + n) * 8 + widx] =
                    (unsigned short)f2bfbits(acc2[j]);
            }
        }
    } else {
        // bias: S16 = sum_{p<16} B^p, B16 = B^16
        const int a = bid - 68;
        const float* Bmat = Bg + a * 4096;
        for (int i = t; i < 4096; i += 256) {
            buf[0][i] = Bmat[i];
            buf[2][i] = ((i >> 6) == (i & 63)) ? 1.f : 0.f;
        }
        __syncthreads();
        int bcur = 0, scur = 2;
        for (int rnd = 0; rnd < 4; ++rnd) {
            mm(buf[scur ^ 1], buf[bcur], buf[scur], buf[scur]);
            mm(buf[bcur ^ 1], buf[bcur], buf[bcur], nullptr);
            __syncthreads();
            scur ^= 1; bcur ^= 1;
        }
        float* vv = buf[3];
        if (t < 64) {
            float acc = 0.f;
            const float* S16 = buf[scur];
            const float* B16 = buf[bcur];
            for (int q = 0; q < 64; ++q)
                acc += Abg[a * 64 + q] * S16[q * 64 + t]
                     + btg[a * 64 + q] * B16[q * 64 + t];
            vv[t] = acc;
        }
        __syncthreads();
        if (t < 128) {
            float accb = bog[a * 128 + t];
            const float* UoA = Uog + a * 8192;
            for (int r = 0; r < 64; ++r) accb += vv[r] * UoA[r * 128 + t];
            biasOut[a * 128 + t] = accb;
        }
    }
}

// ---------------------------------------------------------------------------
// Main GEMM: 1024 blocks x 256 threads (4 waves), block 64M x 256N,
// wave 64x64, BK=64 (34 K-tiles). A-only LDS (2 x 8KB double buffer),
// B-frags global->VGPR from L2-resident pre-packed Wp. One barrier/K-tile.
// ---------------------------------------------------------------------------
__global__ __launch_bounds__(256) void tt_gemm(
    const float* __restrict__ nh,           // (32768,16,128)
    const float* __restrict__ te,           // (32768,128)
    const unsigned short* __restrict__ Wp,  // [34][8][512][8] bf16
    const float* __restrict__ bias,         // [512]
    float* __restrict__ out)                // (32768,512)
{
    __shared__ __align__(16) char Ab[16384];   // [d][kk][slot][row 0..63][16B]

    const int t = threadIdx.x;
    const int lane = t & 63, wave = t >> 6;
    // chunked XCD map: the two n-halves of one m-tile are consecutive lt ->
    // same XCD, ~co-dispatched -> A panel fetched from HBM once, L2 second.
    const int lt = (blockIdx.x & 7) * 128 + (blockIdx.x >> 3);  // 1024 = 8*128
    const int m0 = (lt >> 1) * 64;
    const int wc = (lt & 1) * 4 + wave;          // n-col group 0..7
    const int lx = lane & 15, lg = lane >> 4;

    // A staging: thread -> row r (0..63), k-chunk c (16 f32)
    const int r = t >> 2, c = t & 3;
    const float* nhp = nh + (size_t)(m0 + r) * 2048 + c * 16;
    const float* tep = te + (size_t)(m0 + r) * 128  + c * 16;
    // LDS write base: kk = c>>1, slots 2*(c&1), 2*(c&1)+1
    const int awoff = (c >> 1) * 4096 + (c & 1) * 2048 + r * 16;
    // A frag read base: + d*8192 + kk*4096 + fm*256
    const int aroff = lg * 1024 + lx * 16;

    // B frag source (bytes): + kt*65536 + kk*32768 + fn*256
    const char* const wbase = (const char*)Wp + ((size_t)lg * 512 + wc * 64 + lx) * 16;

    f32x4 acc[4][4] = {};
    float4 va[4];        // staged A f32 (16 floats)
    uint4  bF[4][2];     // B frags [fn][kk]

    auto loadA = [&](int kt) {
        const float* p = (kt < 32) ? (nhp + kt * 64) : (tep + (kt - 32) * 64);
#pragma unroll
        for (int j = 0; j < 4; ++j) va[j] = *(const float4*)(p + 4 * j);
    };
    auto writeA = [&](int d) {
        uint4 w0, w1;
        w0.x = pack2(va[0].x, va[0].y);  w0.y = pack2(va[0].z, va[0].w);
        w0.z = pack2(va[1].x, va[1].y);  w0.w = pack2(va[1].z, va[1].w);
        w1.x = pack2(va[2].x, va[2].y);  w1.y = pack2(va[2].z, va[2].w);
        w1.z = pack2(va[3].x, va[3].y);  w1.w = pack2(va[3].z, va[3].w);
        *(uint4*)(Ab + d * 8192 + awoff)        = w0;
        *(uint4*)(Ab + d * 8192 + awoff + 1024) = w1;
    };
    auto loadB = [&](int kt) {
        const char* q = wbase + (size_t)kt * 65536;
#pragma unroll
        for (int kk = 0; kk < 2; ++kk)
#pragma unroll
            for (int fn = 0; fn < 4; ++fn)
                bF[fn][kk] = *(const uint4*)(q + kk * 32768 + fn * 256);
    };

    // prologue
    loadA(0);
    writeA(0);
    __syncthreads();

    int d = 0;
#pragma unroll 1
    for (int kt = 0; kt < 34; ++kt) {
        const bool more = (kt + 1) < 34;
        if (more) loadA(kt + 1);     // HBM loads, consumed at writeA below
        loadB(kt);                   // L2 loads, consumed by MFMAs

#pragma unroll
        for (int kk = 0; kk < 2; ++kk) {
            bf16x8 aF[4];
#pragma unroll
            for (int fm = 0; fm < 4; ++fm)
                aF[fm] = *(const bf16x8*)(Ab + d * 8192 + kk * 4096 + aroff + fm * 256);
#pragma unroll
            for (int fm = 0; fm < 4; ++fm)
#pragma unroll
                for (int fn = 0; fn < 4; ++fn)
                    acc[fm][fn] = __builtin_amdgcn_mfma_f32_16x16x32_bf16(
                        aF[fm], __builtin_bit_cast(bf16x8, bF[fn][kk]),
                        acc[fm][fn], 0, 0, 0);
        }

        if (more) writeA(d ^ 1);     // cvt + ds_write into the other buffer
        __syncthreads();             // vm ops already consumed -> cheap drain
        d ^= 1;
    }

    // epilogue: C/D layout col = lane&15, row = (lane>>4)*4 + reg  [m89]
    const int orow = m0 + lg * 4;
    const int ocol = wc * 64 + lx;
    float bv[4];
#pragma unroll
    for (int fn = 0; fn < 4; ++fn) bv[fn] = bias[ocol + fn * 16];
#pragma unroll
    for (int fm = 0; fm < 4; ++fm)
#pragma unroll
        for (int fn = 0; fn < 4; ++fn)
#pragma unroll
            for (int j = 0; j < 4; ++j)
                out[(size_t)(orow + fm * 16 + j) * 512 + ocol + fn * 16] =
                    acc[fm][fn][j] + bv[fn];
}

// ---------------------------------------------------------------------------
extern "C" void kernel_launch(void* const* d_in, const int* in_sizes, int n_in,
                              void* d_out, int out_size, void* d_ws, size_t ws_size,
                              hipStream_t stream) {
    const float* nh  = (const float*)d_in[0];
    const float* te  = (const float*)d_in[1];
    const float* Ag  = (const float*)d_in[2];
    const float* Bg  = (const float*)d_in[3];
    const float* Abg = (const float*)d_in[4];
    const float* Utg = (const float*)d_in[5];
    const float* btg = (const float*)d_in[6];
    const float* Uog = (const float*)d_in[7];
    const float* bog = (const float*)d_in[8];

    unsigned short* Wp = (unsigned short*)d_ws;              // 34*8*512*8*2 B
    float* bias = (float*)((char*)d_ws + (size_t)34 * 8 * 512 * 8 * 2);
    float* out = (float*)d_out;

    hipLaunchKernelGGL(tt_fold, dim3(72), dim3(256), 0, stream,
                       Ag, Bg, Abg, Utg, btg, Uog, bog, Wp, bias);
    hipLaunchKernelGGL(tt_gemm, dim3(1024), dim3(256), 0, stream,
                       nh, te, Wp, bias, out);
}

// Round 6
// 225.508 us; speedup vs baseline: 1.4303x; 1.0570x over previous
//
#include <hip/hip_runtime.h>
#include <hip/hip_bf16.h>

// TensorTrainLMN: out[b, a*128+h] = X[b,:] @ W[:, a*128+h] + bias
//   X[b] = [nh[b,0,:128], ..., nh[b,15,:128], te[b,:128]]   (K = 2176)
// tt_fold: folds A@B^(15-c)@U_out (exact f32) into W bf16, PRE-PACKED in MFMA
//   B-fragment order: Wp[kt][slot=k8][n 0..511][8 bf16]. Matmul LDS buffers
//   stride-68 (2-way banks, vs 16-way at stride 64).
// tt_gemm: A-only-LDS MFMA GEMM (W 2.2MB = L2-resident, B-frags global->VGPR).
//   256 thr / 4 waves, block 64Mx256N, wave 64x64, BK=64. Latency schedule:
//   B loads issue-first after each barrier (~300cyc before first MFMA use);
//   A loads distance-2 (va0/va1 named double-buffer, full-iteration in flight).

typedef short bf16x8 __attribute__((ext_vector_type(8)));
typedef float f32x4  __attribute__((ext_vector_type(4)));

__device__ __forceinline__ unsigned f2bfbits(float f) {
    unsigned u = __builtin_bit_cast(unsigned, f);
    return (u + 0x7FFFu + ((u >> 16) & 1u)) >> 16;   // round-to-nearest-even
}
__device__ __forceinline__ unsigned pack2(float a, float b) {
    return f2bfbits(a) | (f2bfbits(b) << 16);
}

// ---------------------------------------------------------------------------
// Fold kernel: 72 blocks x 256 threads. Same math as verified rounds 2-5;
// buffers re-strided to 68 (bank-conflict fix), P in its own region.
// ---------------------------------------------------------------------------
#define FS 68   // fold matmul LDS row stride (floats); 16B-aligned, 2-way banks

__global__ __launch_bounds__(256) void tt_fold(
    const float* __restrict__ Ag,    // (4,128,64)
    const float* __restrict__ Bg,    // (4,64,64)
    const float* __restrict__ Abg,   // (4,1,64)
    const float* __restrict__ Utg,   // (4,128,64)
    const float* __restrict__ btg,   // (4,1,64)
    const float* __restrict__ Uog,   // (4,64,128)
    const float* __restrict__ bog,   // (4,1,128)
    unsigned short* __restrict__ Wp, // [34][8][512][8] bf16
    float* __restrict__ biasOut)     // [512]
{
    __shared__ __align__(16) float L[23552];   // 92 KB, carved below
    const int t = threadIdx.x;
    const int bid = blockIdx.x;

    // d = x @ y (+ add), 64x64, row stride FS. No internal barriers.
    auto mm = [&](float* d, const float* x, const float* y, const float* add) {
        const int r = t >> 2, c0 = (t & 3) << 4;
        float acc[16];
#pragma unroll
        for (int j = 0; j < 16; ++j) acc[j] = 0.f;
        for (int k = 0; k < 64; ++k) {
            const float a = x[r * FS + k];
            const float4* yr = (const float4*)(y + k * FS + c0);
#pragma unroll
            for (int jj = 0; jj < 4; ++jj) {
                float4 v = yr[jj];
                acc[4 * jj + 0] += a * v.x;
                acc[4 * jj + 1] += a * v.y;
                acc[4 * jj + 2] += a * v.z;
                acc[4 * jj + 3] += a * v.w;
            }
        }
        if (add) {
#pragma unroll
            for (int j = 0; j < 16; ++j) acc[j] += add[r * FS + c0 + j];
        }
#pragma unroll
        for (int j = 0; j < 16; ++j) d[r * FS + c0 + j] = acc[j];
    };

    float* buf[4];
    buf[0] = L;
    buf[1] = L + 4352;
    buf[2] = L + 8704;
    buf[3] = L + 13056;
    float* const Pbuf = L + 17408;   // 64x64 dense (stride 64), float4-aligned
    float* const UC   = L + 21504;   // 16x128 staging

    if (bid < 68) {
        int a, p, kbase;
        const float* src;
        if (bid < 64) { a = bid >> 4; const int c = bid & 15; p = 15 - c; kbase = c * 128; src = Ag  + a * 8192; }
        else          { a = bid - 64; p = 16; kbase = 2048;               src = Utg + a * 8192; }
        const float* Bmat = Bg + a * 4096;

        for (int i = t; i < 4096; i += 256) {
            const int row = i >> 6, col = i & 63;
            buf[0][row * FS + col] = Bmat[i];
            buf[2][row * FS + col] = (row == col) ? 1.f : 0.f;
        }
        __syncthreads();
        int bcur = 0, rcur = 2;
        int e = p;
        while (e) {
            if (e & 1) { mm(buf[rcur ^ 1], buf[rcur], buf[bcur], nullptr); rcur ^= 1; __syncthreads(); }
            e >>= 1;
            if (e)     { mm(buf[bcur ^ 1], buf[bcur], buf[bcur], nullptr); bcur ^= 1; __syncthreads(); }
        }

        // copy P = B^p to dense stride-64 region (no overlap, no dance)
        {
            const int prow = t >> 2, pc0 = (t & 3) << 4;
#pragma unroll
            for (int j = 0; j < 16; ++j)
                Pbuf[prow * 64 + pc0 + j] = buf[rcur][prow * FS + pc0 + j];
        }
        __syncthreads();

        // M1 = src(128x64) @ P, stored stride-65 at L (bufs dead now)
        float* M1 = L;
        {
            const int i = t >> 1, r0 = (t & 1) << 5;
            float acc[32];
#pragma unroll
            for (int j = 0; j < 32; ++j) acc[j] = 0.f;
            for (int q = 0; q < 64; ++q) {
                const float av = src[i * 64 + q];
                const float4* pr = (const float4*)(Pbuf + q * 64 + r0);
#pragma unroll
                for (int jj = 0; jj < 8; ++jj) {
                    float4 v = pr[jj];
                    acc[4 * jj + 0] += av * v.x;
                    acc[4 * jj + 1] += av * v.y;
                    acc[4 * jj + 2] += av * v.z;
                    acc[4 * jj + 3] += av * v.w;
                }
            }
#pragma unroll
            for (int j = 0; j < 32; ++j) M1[i * 65 + r0 + j] = acc[j];
        }
        __syncthreads();

        // W2 = M1(128x64) @ Uo(64x128); Uo staged 16 rows/chunk
        const float* UoA = Uog + a * 8192;
        const int i = t >> 1, h0 = (t & 1) << 6;
        float acc2[64];
#pragma unroll
        for (int j = 0; j < 64; ++j) acc2[j] = 0.f;
        for (int ch = 0; ch < 4; ++ch) {
            __syncthreads();
            for (int idx = t; idx < 2048; idx += 256) UC[idx] = UoA[ch * 2048 + idx];
            __syncthreads();
            for (int rr = 0; rr < 16; ++rr) {
                const float m = M1[i * 65 + ch * 16 + rr];
                const float4* ur = (const float4*)(UC + rr * 128 + h0);
#pragma unroll
                for (int jj = 0; jj < 16; ++jj) {
                    float4 v = ur[jj];
                    acc2[4 * jj + 0] += m * v.x;
                    acc2[4 * jj + 1] += m * v.y;
                    acc2[4 * jj + 2] += m * v.z;
                    acc2[4 * jj + 3] += m * v.w;
                }
            }
        }
        // write fragment-ordered image: [kt][slot][n][widx]
        {
            const int k = kbase + i;
            const int kt = k >> 6, slot = (k >> 3) & 7, widx = k & 7;
#pragma unroll
            for (int j = 0; j < 64; ++j) {
                const int n = a * 128 + h0 + j;
                Wp[((size_t)(kt * 8 + slot) * 512 + n) * 8 + widx] =
                    (unsigned short)f2bfbits(acc2[j]);
            }
        }
    } else {
        // bias: S16 = sum_{p<16} B^p, B16 = B^16
        const int a = bid - 68;
        const float* Bmat = Bg + a * 4096;
        for (int i = t; i < 4096; i += 256) {
            const int row = i >> 6, col = i & 63;
            buf[0][row * FS + col] = Bmat[i];
            buf[2][row * FS + col] = (row == col) ? 1.f : 0.f;
        }
        __syncthreads();
        int bcur = 0, scur = 2;
        for (int rnd = 0; rnd < 4; ++rnd) {
            mm(buf[scur ^ 1], buf[bcur], buf[scur], buf[scur]);
            mm(buf[bcur ^ 1], buf[bcur], buf[bcur], nullptr);
            __syncthreads();
            scur ^= 1; bcur ^= 1;
        }
        float* vv = Pbuf;
        if (t < 64) {
            float acc = 0.f;
            const float* S16 = buf[scur];
            const float* B16 = buf[bcur];
            for (int q = 0; q < 64; ++q)
                acc += Abg[a * 64 + q] * S16[q * FS + t]
                     + btg[a * 64 + q] * B16[q * FS + t];
            vv[t] = acc;
        }
        __syncthreads();
        if (t < 128) {
            float accb = bog[a * 128 + t];
            const float* UoA = Uog + a * 8192;
            for (int r = 0; r < 64; ++r) accb += vv[r] * UoA[r * 128 + t];
            biasOut[a * 128 + t] = accb;
        }
    }
}
#undef FS

// ---------------------------------------------------------------------------
// Main GEMM: 1024 blocks x 256 threads (4 waves), block 64M x 256N,
// wave 64x64, BK=64 (34 K-tiles). A-only LDS (2 x 8KB). B-frags from
// L2-resident Wp, issued FIRST each iteration. A loads distance-2 via
// named va0/va1 register double-buffer (manual 2x unroll, static indexing).
// ---------------------------------------------------------------------------
__global__ __launch_bounds__(256) void tt_gemm(
    const float* __restrict__ nh,           // (32768,16,128)
    const float* __restrict__ te,           // (32768,128)
    const unsigned short* __restrict__ Wp,  // [34][8][512][8] bf16
    const float* __restrict__ bias,         // [512]
    float* __restrict__ out)                // (32768,512)
{
    __shared__ __align__(16) char Ab[16384];   // [d][kk][lg][row 0..63][16B]

    const int t = threadIdx.x;
    const int lane = t & 63, wave = t >> 6;
    // chunked XCD map: the two n-halves of one m-tile land on the same XCD.
    const int lt = (blockIdx.x & 7) * 128 + (blockIdx.x >> 3);  // 1024 = 8*128
    const int m0 = (lt >> 1) * 64;
    const int wc = (lt & 1) * 4 + wave;          // n-col group 0..7
    const int lx = lane & 15, lg = lane >> 4;

    // A staging: thread -> row r (0..63), k-chunk c (16 f32)
    const int r = t >> 2, c = t & 3;
    const float* nhp = nh + (size_t)(m0 + r) * 2048 + c * 16;
    const float* tep = te + (size_t)(m0 + r) * 128  + c * 16;
    const int awoff = (c >> 1) * 4096 + (c & 1) * 2048 + r * 16;  // +1024 2nd run
    const int aroff = lg * 1024 + lx * 16;       // + d*8192 + kk*4096 + fm*256

    // B frag byte base: + kt*65536 + kk*32768 + fn*256
    const char* const wbase = (const char*)Wp + lg * 8192 + wc * 1024 + lx * 16;

    f32x4 acc[4][4] = {};
    float4 va0[4], va1[4];   // named A staging buffers (distance-2 pipeline)
    uint4  bF[4][2];         // B frags [fn][kk]

#define LOADA(dst, kt_) do {                                                   \
    const float* _p = ((kt_) < 32) ? (nhp + (kt_) * 64) : (tep + ((kt_) - 32) * 64); \
    _Pragma("unroll")                                                          \
    for (int _j = 0; _j < 4; ++_j) dst[_j] = *(const float4*)(_p + 4 * _j);    \
} while (0)

#define WRITEA(src, d_) do {                                                   \
    uint4 _w0, _w1;                                                            \
    _w0.x = pack2(src[0].x, src[0].y);  _w0.y = pack2(src[0].z, src[0].w);     \
    _w0.z = pack2(src[1].x, src[1].y);  _w0.w = pack2(src[1].z, src[1].w);     \
    _w1.x = pack2(src[2].x, src[2].y);  _w1.y = pack2(src[2].z, src[2].w);     \
    _w1.z = pack2(src[3].x, src[3].y);  _w1.w = pack2(src[3].z, src[3].w);     \
    *(uint4*)(Ab + (d_) * 8192 + awoff)        = _w0;                          \
    *(uint4*)(Ab + (d_) * 8192 + awoff + 1024) = _w1;                          \
} while (0)

#define LOADB(kt_) do {                                                        \
    const char* _q = wbase + (size_t)(kt_) * 65536;                            \
    _Pragma("unroll")                                                          \
    for (int _kk = 0; _kk < 2; ++_kk)                                          \
        _Pragma("unroll")                                                      \
        for (int _fn = 0; _fn < 4; ++_fn)                                      \
            bF[_fn][_kk] = *(const uint4*)(_q + _kk * 32768 + _fn * 256);      \
} while (0)

#define COMPUTE(d_) do {                                                       \
    _Pragma("unroll")                                                          \
    for (int _kk = 0; _kk < 2; ++_kk) {                                        \
        bf16x8 _aF[4];                                                         \
        _Pragma("unroll")                                                      \
        for (int _fm = 0; _fm < 4; ++_fm)                                      \
            _aF[_fm] = *(const bf16x8*)(Ab + (d_) * 8192 + _kk * 4096 + aroff + _fm * 256); \
        _Pragma("unroll")                                                      \
        for (int _fm = 0; _fm < 4; ++_fm)                                      \
            _Pragma("unroll")                                                  \
            for (int _fn = 0; _fn < 4; ++_fn)                                  \
                acc[_fm][_fn] = __builtin_amdgcn_mfma_f32_16x16x32_bf16(       \
                    _aF[_fm], __builtin_bit_cast(bf16x8, bF[_fn][_kk]),        \
                    acc[_fm][_fn], 0, 0, 0);                                   \
    }                                                                          \
} while (0)

    // prologue: tile 0 -> buf0 via va0; tile 1 in flight in va1
    LOADA(va0, 0);
    WRITEA(va0, 0);
    LOADA(va1, 1);
    __syncthreads();

#pragma unroll 1
    for (int kt = 0; kt < 34; kt += 2) {
        // ---- even iter: reads buf0 (tile kt); writes buf1 (tile kt+1) ----
        LOADB(kt);                        // issue-first: in flight before MFMAs
        if (kt + 2 < 34) LOADA(va0, kt + 2);
        COMPUTE(0);
        WRITEA(va1, 1);                   // va1 loaded a full iteration ago
        __syncthreads();

        // ---- odd iter: reads buf1 (tile kt+1); writes buf0 (tile kt+2) ----
        LOADB(kt + 1);
        if (kt + 3 < 34) LOADA(va1, kt + 3);
        COMPUTE(1);
        if (kt + 2 < 34) WRITEA(va0, 0);
        __syncthreads();
    }
#undef LOADA
#undef WRITEA
#undef LOADB
#undef COMPUTE

    // epilogue: C/D layout col = lane&15, row = (lane>>4)*4 + reg  [m89]
    const int orow = m0 + lg * 4;
    const int ocol = wc * 64 + lx;
    float bv[4];
#pragma unroll
    for (int fn = 0; fn < 4; ++fn) bv[fn] = bias[ocol + fn * 16];
#pragma unroll
    for (int fm = 0; fm < 4; ++fm)
#pragma unroll
        for (int fn = 0; fn < 4; ++fn)
#pragma unroll
            for (int j = 0; j < 4; ++j)
                out[(size_t)(orow + fm * 16 + j) * 512 + ocol + fn * 16] =
                    acc[fm][fn][j] + bv[fn];
}

// ---------------------------------------------------------------------------
extern "C" void kernel_launch(void* const* d_in, const int* in_sizes, int n_in,
                              void* d_out, int out_size, void* d_ws, size_t ws_size,
                              hipStream_t stream) {
    const float* nh  = (const float*)d_in[0];
    const float* te  = (const float*)d_in[1];
    const float* Ag  = (const float*)d_in[2];
    const float* Bg  = (const float*)d_in[3];
    const float* Abg = (const float*)d_in[4];
    const float* Utg = (const float*)d_in[5];
    const float* btg = (const float*)d_in[6];
    const float* Uog = (const float*)d_in[7];
    const float* bog = (const float*)d_in[8];

    unsigned short* Wp = (unsigned short*)d_ws;              // 34*8*512*8*2 B
    float* bias = (float*)((char*)d_ws + (size_t)34 * 8 * 512 * 8 * 2);
    float* out = (float*)d_out;

    hipLaunchKernelGGL(tt_fold, dim3(72), dim3(256), 0, stream,
                       Ag, Bg, Abg, Utg, btg, Uog, bog, Wp, bias);
    hipLaunchKernelGGL(tt_gemm, dim3(1024), dim3(256), 0, stream,
                       nh, te, Wp, bias, out);
}